// Round 5
// baseline (230.676 us; speedup 1.0000x reference)
//
#include <hip/hip_runtime.h>
#include <hip/hip_fp16.h>
#include <math.h>

#define NNODES 50000
#define NF     128
#define NEDGES 800000

#define NTILES ((NNODES + 31) / 32)          // 1563
#define NODE_CAP 64                          // total slots per node (8 XCD segs x 8)
#define SEG 8                                // slots per XCD segment
#define OVF_CAP 16                           // overflow slots per node
#define CPAD 32                              // r4 fallback counter stride
#define GEMM_BLOCKS 512

__device__ __forceinline__ unsigned bf16_rne(float f) {
    unsigned u = __float_as_uint(f);
    return (u + 0x7FFFu + ((u >> 16) & 1u)) >> 16;
}

struct alignas(8) half4v { __half2 lo, hi; };

__device__ __forceinline__ void gath(float4& acc, unsigned rv,
                                     const __half* __restrict__ xh, int j0) {
    const half4v v = *(const half4v*)(xh + (size_t)(rv & 0xFFFFu) * NF + j0);
    const float w = __uint_as_float(rv & 0xFFFF0000u);
    const float2 f0 = __half22float2(v.lo), f1 = __half22float2(v.hi);
    acc.x += w * f0.x; acc.y += w * f0.y; acc.z += w * f1.x; acc.w += w * f1.y;
}

// ======== bin fill with per-XCD L2-LOCAL atomics + x->fp16 convert =========
// Theory (r0-r4 ledger): bin stage constant ~130us == 800K device-scope
// returning atomics at ~6.2 G/s — an aggregate retire-rate cap at the
// cross-XCD coherence point (invariant to ILP, store type, line spreading).
// Fix: replica counters per physical XCD, updated with WORKGROUP-scope
// atomics -> executed in the local (per-XCD) L2, never crossing the
// coherence point. Replica r is only touched by blocks on XCD r (real
// XCC_ID, not blockIdx heuristics) so L2-bank atomicity suffices; kernel
// boundary release/acquire publishes results. Rare segment overflow
// (P~2e-4 per node-xcd cell) spills to a device-atomic bin (~100 ops).
__global__ __launch_bounds__(256) void bin_fill_xcd(const int* __restrict__ src,
                                                    const int* __restrict__ dst,
                                                    const float* __restrict__ ew,
                                                    const float* __restrict__ alpha_p,
                                                    const float* __restrict__ x,
                                                    int* __restrict__ cnt8,
                                                    int* __restrict__ ovf_cnt,
                                                    unsigned* __restrict__ rec,
                                                    unsigned* __restrict__ ovf_rec,
                                                    __half* __restrict__ xh) {
    int e = blockIdx.x * 256 + threadIdx.x;
    if (e >= NEDGES) return;

    // ---- convert 8 x elements -> fp16 (streamed, coalesced) ----
    {
        const float4 a = *(const float4*)(x + (size_t)e * 8);
        const float4 b = *(const float4*)(x + (size_t)e * 8 + 4);
        __half2 p0 = __floats2half2_rn(a.x, a.y);
        __half2 p1 = __floats2half2_rn(a.z, a.w);
        __half2 p2 = __floats2half2_rn(b.x, b.y);
        __half2 p3 = __floats2half2_rn(b.z, b.w);
        uint4 o;
        o.x = *(const unsigned*)&p0;
        o.y = *(const unsigned*)&p1;
        o.z = *(const unsigned*)&p2;
        o.w = *(const unsigned*)&p3;
        *(uint4*)(xh + (size_t)e * 8) = o;
    }

    // ---- physical XCD id (wave-uniform; HW-verified readable on gfx950) ----
    unsigned xcc;
    asm volatile("s_getreg_b32 %0, hwreg(HW_REG_XCC_ID, 0, 32)" : "=s"(xcc));
    xcc &= 7u;

    const int d = dst[e];
    const unsigned recv = (bf16_rne((1.0f - alpha_p[0]) * ew[e]) << 16) |
                          (unsigned)src[e];

    // L2-local (workgroup-scope) returning atomic: never leaves this XCD's L2
    const int pos = __hip_atomic_fetch_add(&cnt8[(size_t)d * 8 + xcc], 1,
                                           __ATOMIC_RELAXED,
                                           __HIP_MEMORY_SCOPE_WORKGROUP);
    if (pos < SEG) {
        rec[(size_t)d * NODE_CAP + xcc * SEG + pos] = recv;
    } else {
        // rare spill: device-scope atomic (~100 total, negligible)
        const int p2 = atomicAdd(&ovf_cnt[d], 1);
        if (p2 < OVF_CAP) ovf_rec[(size_t)d * OVF_CAP + p2] = recv;
    }
}

// ==== fused: 8-segment bin gather (fp16) + 32x128 GEMM + epilogue ==========
__global__ __launch_bounds__(256)
void fused_bin8(const float* __restrict__ x,
                const __half* __restrict__ xh,
                const float* __restrict__ h0,
                const float* __restrict__ alpha_p,
                const float* __restrict__ lamda_p,
                const int* __restrict__ l_p,
                const int* __restrict__ cnt8,
                const int* __restrict__ ovf_cnt,
                const unsigned* __restrict__ rec,
                const unsigned* __restrict__ ovf_rec,
                const float* __restrict__ W,
                float* __restrict__ out) {
    __shared__ float sT[32 * NF];   // 16 KB, row-major [row][feat]

    const int tid   = threadIdx.x;
    const int wave  = tid >> 6;
    const int lane  = tid & 63;
    const int eh    = lane >> 5;           // half-wave id -> node parity
    const int j0    = (lane & 31) * 4;     // 4-feature chunk
    const int rbase = blockIdx.x * 32;
    const float alpha = alpha_p[0];

    const int nbase = rbase + wave * 8 + eh;

    #pragma unroll
    for (int q = 0; q < 4; q++) {
        const int node = nbase + 2 * q;
        const int rl   = wave * 8 + 2 * q + eh;

        float4 acc = make_float4(0.f, 0.f, 0.f, 0.f);
        if (node < NNODES) {
            const float4 h = *(const float4*)(h0 + (size_t)node * NF + j0);
            acc.x = alpha * h.x;
            acc.y = alpha * h.y;
            acc.z = alpha * h.z;
            acc.w = alpha * h.w;

            const unsigned* brec = rec + (size_t)node * NODE_CAP;
            const int4 ca = *(const int4*)(cnt8 + (size_t)node * 8);
            const int4 cb = *(const int4*)(cnt8 + (size_t)node * 8 + 4);
            const int cc[8] = { ca.x, ca.y, ca.z, ca.w, cb.x, cb.y, cb.z, cb.w };

            #pragma unroll
            for (int r = 0; r < 8; r++) {
                const int cr = min(cc[r], SEG);     // node-uniform -> cheap branches
                const unsigned* seg = brec + r * SEG;
                int i = 0;
                for (; i + 1 < cr; i += 2) {
                    const unsigned r0 = seg[i];
                    const unsigned r1 = seg[i + 1];
                    gath(acc, r0, xh, j0);
                    gath(acc, r1, xh, j0);
                }
                if (i < cr) gath(acc, seg[i], xh, j0);
            }
            {   // overflow segment (almost always empty)
                const int co = min(ovf_cnt[node], OVF_CAP);
                const unsigned* oseg = ovf_rec + (size_t)node * OVF_CAP;
                int i = 0;
                for (; i + 1 < co; i += 2) {
                    const unsigned r0 = oseg[i];
                    const unsigned r1 = oseg[i + 1];
                    gath(acc, r0, xh, j0);
                    gath(acc, r1, xh, j0);
                }
                if (i < co) gath(acc, oseg[i], xh, j0);
            }
        }
        *(float4*)&sT[rl * NF + j0] = acc;
    }
    __syncthreads();

    // ---- phase 2: 32x128 tile GEMM (unchanged, proven) ----
    const int cg_  = tid & 31;
    const int slot = tid >> 5;
    const int jj   = cg_ * 4;
    const int r0_  = slot * 4;

    float acc[4][4];
    #pragma unroll
    for (int r = 0; r < 4; r++)
        #pragma unroll
        for (int c = 0; c < 4; c++) acc[r][c] = 0.f;

    #pragma unroll 4
    for (int k = 0; k < NF; k++) {
        const float4 w = *(const float4*)(W + k * NF + jj);   // L1/L2 hit
        const float s0 = sT[(r0_ + 0) * NF + k];              // broadcast reads
        const float s1 = sT[(r0_ + 1) * NF + k];
        const float s2 = sT[(r0_ + 2) * NF + k];
        const float s3 = sT[(r0_ + 3) * NF + k];
        acc[0][0] += s0 * w.x; acc[0][1] += s0 * w.y; acc[0][2] += s0 * w.z; acc[0][3] += s0 * w.w;
        acc[1][0] += s1 * w.x; acc[1][1] += s1 * w.y; acc[1][2] += s1 * w.z; acc[1][3] += s1 * w.w;
        acc[2][0] += s2 * w.x; acc[2][1] += s2 * w.y; acc[2][2] += s2 * w.z; acc[2][3] += s2 * w.w;
        acc[3][0] += s3 * w.x; acc[3][1] += s3 * w.y; acc[3][2] += s3 * w.z; acc[3][3] += s3 * w.w;
    }

    const float theta = logf(lamda_p[0] / (float)l_p[0] + 1.0f);
    const float omt   = 1.0f - theta;

    #pragma unroll
    for (int r = 0; r < 4; r++) {
        const int row = rbase + r0_ + r;
        if (row < NNODES) {
            const float4 xv = *(const float4*)(x + (size_t)row * NF + jj);
            const float4 s  = *(const float4*)&sT[(r0_ + r) * NF + jj];
            float4 o;
            o.x = theta * acc[r][0] + omt * s.x + xv.x;
            o.y = theta * acc[r][1] + omt * s.y + xv.y;
            o.z = theta * acc[r][2] + omt * s.z + xv.z;
            o.w = theta * acc[r][3] + omt * s.w + xv.w;
            *(float4*)(out + (size_t)row * NF + jj) = o;
        }
    }
}

// ============ r4 fallback: padded counters, device atomics =================

__global__ __launch_bounds__(256) void bin_fill_conv_pad(const int* __restrict__ src,
                                                         const int* __restrict__ dst,
                                                         const float* __restrict__ ew,
                                                         const float* __restrict__ alpha_p,
                                                         const float* __restrict__ x,
                                                         int* __restrict__ cnt,
                                                         unsigned* __restrict__ rec,
                                                         __half* __restrict__ xh) {
    int e = blockIdx.x * 256 + threadIdx.x;
    if (e >= NEDGES) return;
    {
        const float4 a = *(const float4*)(x + (size_t)e * 8);
        const float4 b = *(const float4*)(x + (size_t)e * 8 + 4);
        __half2 p0 = __floats2half2_rn(a.x, a.y);
        __half2 p1 = __floats2half2_rn(a.z, a.w);
        __half2 p2 = __floats2half2_rn(b.x, b.y);
        __half2 p3 = __floats2half2_rn(b.z, b.w);
        uint4 o;
        o.x = *(const unsigned*)&p0;
        o.y = *(const unsigned*)&p1;
        o.z = *(const unsigned*)&p2;
        o.w = *(const unsigned*)&p3;
        *(uint4*)(xh + (size_t)e * 8) = o;
    }
    const int d = dst[e];
    const int pos = atomicAdd(&cnt[(size_t)d * CPAD], 1);
    if (pos < NODE_CAP) {
        const unsigned wb = bf16_rne((1.0f - alpha_p[0]) * ew[e]);
        rec[(size_t)d * NODE_CAP + pos] = (wb << 16) | (unsigned)src[e];
    }
}

__global__ __launch_bounds__(256)
void fused_bin7(const float* __restrict__ x,
                const __half* __restrict__ xh,
                const float* __restrict__ h0,
                const float* __restrict__ alpha_p,
                const float* __restrict__ lamda_p,
                const int* __restrict__ l_p,
                const int* __restrict__ cnt,
                const unsigned* __restrict__ rec,
                const float* __restrict__ W,
                float* __restrict__ out) {
    __shared__ float sT[32 * NF];

    const int tid   = threadIdx.x;
    const int wave  = tid >> 6;
    const int lane  = tid & 63;
    const int eh    = lane >> 5;
    const int j0    = (lane & 31) * 4;
    const int rbase = blockIdx.x * 32;
    const float alpha = alpha_p[0];

    const int nbase = rbase + wave * 8 + eh;

    int cnts[4];
    #pragma unroll
    for (int q = 0; q < 4; q++) {
        const int node = nbase + 2 * q;
        cnts[q] = (node < NNODES) ? cnt[(size_t)node * CPAD] : 0;
    }

    #pragma unroll
    for (int q = 0; q < 4; q++) {
        const int node = nbase + 2 * q;
        const int rl   = wave * 8 + 2 * q + eh;

        float4 acc = make_float4(0.f, 0.f, 0.f, 0.f);
        if (node < NNODES) {
            const float4 h = *(const float4*)(h0 + (size_t)node * NF + j0);
            acc.x = alpha * h.x;
            acc.y = alpha * h.y;
            acc.z = alpha * h.z;
            acc.w = alpha * h.w;

            const int count = min(cnts[q], NODE_CAP);
            const unsigned* brec = rec + (size_t)node * NODE_CAP;
            int i = 0;
            for (; i + 3 < count; i += 4) {
                const uint4 r = *(const uint4*)(brec + i);
                gath(acc, r.x, xh, j0);
                gath(acc, r.y, xh, j0);
                gath(acc, r.z, xh, j0);
                gath(acc, r.w, xh, j0);
            }
            for (; i < count; i++) gath(acc, brec[i], xh, j0);
        }
        *(float4*)&sT[rl * NF + j0] = acc;
    }
    __syncthreads();

    const int cg_  = tid & 31;
    const int slot = tid >> 5;
    const int jj   = cg_ * 4;
    const int r0_  = slot * 4;

    float acc[4][4];
    #pragma unroll
    for (int r = 0; r < 4; r++)
        #pragma unroll
        for (int c = 0; c < 4; c++) acc[r][c] = 0.f;

    #pragma unroll 4
    for (int k = 0; k < NF; k++) {
        const float4 w = *(const float4*)(W + k * NF + jj);
        const float s0 = sT[(r0_ + 0) * NF + k];
        const float s1 = sT[(r0_ + 1) * NF + k];
        const float s2 = sT[(r0_ + 2) * NF + k];
        const float s3 = sT[(r0_ + 3) * NF + k];
        acc[0][0] += s0 * w.x; acc[0][1] += s0 * w.y; acc[0][2] += s0 * w.z; acc[0][3] += s0 * w.w;
        acc[1][0] += s1 * w.x; acc[1][1] += s1 * w.y; acc[1][2] += s1 * w.z; acc[1][3] += s1 * w.w;
        acc[2][0] += s2 * w.x; acc[2][1] += s2 * w.y; acc[2][2] += s2 * w.z; acc[2][3] += s2 * w.w;
        acc[3][0] += s3 * w.x; acc[3][1] += s3 * w.y; acc[3][2] += s3 * w.z; acc[3][3] += s3 * w.w;
    }

    const float theta = logf(lamda_p[0] / (float)l_p[0] + 1.0f);
    const float omt   = 1.0f - theta;

    #pragma unroll
    for (int r = 0; r < 4; r++) {
        const int row = rbase + r0_ + r;
        if (row < NNODES) {
            const float4 xv = *(const float4*)(x + (size_t)row * NF + jj);
            const float4 s  = *(const float4*)&sT[(r0_ + r) * NF + jj];
            float4 o;
            o.x = theta * acc[r][0] + omt * s.x + xv.x;
            o.y = theta * acc[r][1] + omt * s.y + xv.y;
            o.z = theta * acc[r][2] + omt * s.z + xv.z;
            o.w = theta * acc[r][3] + omt * s.w + xv.w;
            *(float4*)(out + (size_t)row * NF + jj) = o;
        }
    }
}

// ============ r2 fallback: unpadded counters ================================

__global__ __launch_bounds__(256) void bin_fill_conv(const int* __restrict__ src,
                                                     const int* __restrict__ dst,
                                                     const float* __restrict__ ew,
                                                     const float* __restrict__ alpha_p,
                                                     const float* __restrict__ x,
                                                     int* __restrict__ cnt,
                                                     unsigned* __restrict__ rec,
                                                     __half* __restrict__ xh) {
    int e = blockIdx.x * 256 + threadIdx.x;
    if (e >= NEDGES) return;
    {
        const float4 a = *(const float4*)(x + (size_t)e * 8);
        const float4 b = *(const float4*)(x + (size_t)e * 8 + 4);
        __half2 p0 = __floats2half2_rn(a.x, a.y);
        __half2 p1 = __floats2half2_rn(a.z, a.w);
        __half2 p2 = __floats2half2_rn(b.x, b.y);
        __half2 p3 = __floats2half2_rn(b.z, b.w);
        uint4 o;
        o.x = *(const unsigned*)&p0;
        o.y = *(const unsigned*)&p1;
        o.z = *(const unsigned*)&p2;
        o.w = *(const unsigned*)&p3;
        *(uint4*)(xh + (size_t)e * 8) = o;
    }
    const int d = dst[e];
    const int pos = atomicAdd(&cnt[d], 1);
    if (pos < NODE_CAP) {
        const unsigned wb = bf16_rne((1.0f - alpha_p[0]) * ew[e]);
        rec[(size_t)d * NODE_CAP + pos] = (wb << 16) | (unsigned)src[e];
    }
}

__global__ __launch_bounds__(256)
void fused_bin6(const float* __restrict__ x,
                const __half* __restrict__ xh,
                const float* __restrict__ h0,
                const float* __restrict__ alpha_p,
                const float* __restrict__ lamda_p,
                const int* __restrict__ l_p,
                const int* __restrict__ cnt,
                const unsigned* __restrict__ rec,
                const float* __restrict__ W,
                float* __restrict__ out) {
    __shared__ float sT[32 * NF];

    const int tid   = threadIdx.x;
    const int wave  = tid >> 6;
    const int lane  = tid & 63;
    const int eh    = lane >> 5;
    const int j0    = (lane & 31) * 4;
    const int rbase = blockIdx.x * 32;
    const float alpha = alpha_p[0];

    const int nbase = rbase + wave * 8 + eh;

    int cnts[4];
    #pragma unroll
    for (int q = 0; q < 4; q++) {
        const int node = nbase + 2 * q;
        cnts[q] = (node < NNODES) ? cnt[node] : 0;
    }

    #pragma unroll
    for (int q = 0; q < 4; q++) {
        const int node = nbase + 2 * q;
        const int rl   = wave * 8 + 2 * q + eh;

        float4 acc = make_float4(0.f, 0.f, 0.f, 0.f);
        if (node < NNODES) {
            const float4 h = *(const float4*)(h0 + (size_t)node * NF + j0);
            acc.x = alpha * h.x;
            acc.y = alpha * h.y;
            acc.z = alpha * h.z;
            acc.w = alpha * h.w;

            const int count = min(cnts[q], NODE_CAP);
            const unsigned* brec = rec + (size_t)node * NODE_CAP;
            int i = 0;
            for (; i + 3 < count; i += 4) {
                const uint4 r = *(const uint4*)(brec + i);
                gath(acc, r.x, xh, j0);
                gath(acc, r.y, xh, j0);
                gath(acc, r.z, xh, j0);
                gath(acc, r.w, xh, j0);
            }
            for (; i < count; i++) gath(acc, brec[i], xh, j0);
        }
        *(float4*)&sT[rl * NF + j0] = acc;
    }
    __syncthreads();

    const int cg_  = tid & 31;
    const int slot = tid >> 5;
    const int jj   = cg_ * 4;
    const int r0_  = slot * 4;

    float acc[4][4];
    #pragma unroll
    for (int r = 0; r < 4; r++)
        #pragma unroll
        for (int c = 0; c < 4; c++) acc[r][c] = 0.f;

    #pragma unroll 4
    for (int k = 0; k < NF; k++) {
        const float4 w = *(const float4*)(W + k * NF + jj);
        const float s0 = sT[(r0_ + 0) * NF + k];
        const float s1 = sT[(r0_ + 1) * NF + k];
        const float s2 = sT[(r0_ + 2) * NF + k];
        const float s3 = sT[(r0_ + 3) * NF + k];
        acc[0][0] += s0 * w.x; acc[0][1] += s0 * w.y; acc[0][2] += s0 * w.z; acc[0][3] += s0 * w.w;
        acc[1][0] += s1 * w.x; acc[1][1] += s1 * w.y; acc[1][2] += s1 * w.z; acc[1][3] += s1 * w.w;
        acc[2][0] += s2 * w.x; acc[2][1] += s2 * w.y; acc[2][2] += s2 * w.z; acc[2][3] += s2 * w.w;
        acc[3][0] += s3 * w.x; acc[3][1] += s3 * w.y; acc[3][2] += s3 * w.z; acc[3][3] += s3 * w.w;
    }

    const float theta = logf(lamda_p[0] / (float)l_p[0] + 1.0f);
    const float omt   = 1.0f - theta;

    #pragma unroll
    for (int r = 0; r < 4; r++) {
        const int row = rbase + r0_ + r;
        if (row < NNODES) {
            const float4 xv = *(const float4*)(x + (size_t)row * NF + jj);
            const float4 s  = *(const float4*)&sT[(r0_ + r) * NF + jj];
            float4 o;
            o.x = theta * acc[r][0] + omt * s.x + xv.x;
            o.y = theta * acc[r][1] + omt * s.y + xv.y;
            o.z = theta * acc[r][2] + omt * s.z + xv.z;
            o.w = theta * acc[r][3] + omt * s.w + xv.w;
            *(float4*)(out + (size_t)row * NF + jj) = o;
        }
    }
}

// ===================== round-1 ultimate fallback =============================

__global__ __launch_bounds__(256) void init_support(const float* __restrict__ h0,
                                                    const float* __restrict__ alpha_p,
                                                    float* __restrict__ S) {
    const float alpha = alpha_p[0];
    int i = (blockIdx.x * 256 + threadIdx.x) * 4;
    if (i < NNODES * NF) {
        float4 h = *(const float4*)(h0 + i);
        float4 v;
        v.x = alpha * h.x; v.y = alpha * h.y; v.z = alpha * h.z; v.w = alpha * h.w;
        *(float4*)(S + i) = v;
    }
}

__global__ __launch_bounds__(256) void scatter_edges(const float* __restrict__ x,
                                                     const float* __restrict__ ew,
                                                     const int* __restrict__ src,
                                                     const int* __restrict__ dst,
                                                     const float* __restrict__ alpha_p,
                                                     float* __restrict__ S) {
    int gid  = blockIdx.x * 256 + threadIdx.x;
    int e    = gid >> 5;
    int lane = gid & 31;
    if (e >= NEDGES) return;
    const float coef = (1.0f - alpha_p[0]) * ew[e];
    const int s = src[e];
    const int d = dst[e];
    const float4 xs = *(const float4*)(x + (long)s * NF + lane * 4);
    float* outp = S + (long)d * NF + lane * 4;
    unsafeAtomicAdd(outp + 0, coef * xs.x);
    unsafeAtomicAdd(outp + 1, coef * xs.y);
    unsafeAtomicAdd(outp + 2, coef * xs.z);
    unsafeAtomicAdd(outp + 3, coef * xs.w);
}

__global__ __launch_bounds__(256) void gemm_out(float* __restrict__ S,
                                                const float* __restrict__ W,
                                                const float* __restrict__ x,
                                                const float* __restrict__ lamda_p,
                                                const int* __restrict__ l_p) {
    __shared__ float Wl[NF * NF];
    __shared__ float sT[NF * 32];
    const int tid = threadIdx.x;
    {
        const float4* Wv = (const float4*)W;
        float4* Wlv = (float4*)Wl;
        #pragma unroll
        for (int i = 0; i < 16; i++) Wlv[tid + i * 256] = Wv[tid + i * 256];
    }
    const float theta = logf(lamda_p[0] / (float)l_p[0] + 1.0f);
    const float omt   = 1.0f - theta;
    const int cg_ = tid & 31, slot = tid >> 5;
    const int j0 = cg_ * 4, rl0 = slot * 4;
    const int rl = tid & 31, c0 = (tid >> 5) * 16;

    for (int t = blockIdx.x; t < NTILES; t += GEMM_BLOCKS) {
        const int rbase = t * 32;
        {
            const int row = rbase + rl;
            #pragma unroll
            for (int cc = 0; cc < 16; cc += 4) {
                const int c = c0 + cc;
                float4 v = (row < NNODES) ? *(const float4*)(S + (size_t)row * NF + c)
                                          : make_float4(0.f, 0.f, 0.f, 0.f);
                sT[(c + 0) * 32 + rl] = v.x;
                sT[(c + 1) * 32 + rl] = v.y;
                sT[(c + 2) * 32 + rl] = v.z;
                sT[(c + 3) * 32 + rl] = v.w;
            }
        }
        __syncthreads();
        float acc[4][4];
        #pragma unroll
        for (int r = 0; r < 4; r++)
            #pragma unroll
            for (int c = 0; c < 4; c++) acc[r][c] = 0.f;
        #pragma unroll 4
        for (int k = 0; k < NF; k++) {
            float4 w = *(const float4*)&Wl[k * NF + j0];
            float4 s = *(const float4*)&sT[k * 32 + rl0];
            acc[0][0] += s.x * w.x; acc[0][1] += s.x * w.y; acc[0][2] += s.x * w.z; acc[0][3] += s.x * w.w;
            acc[1][0] += s.y * w.x; acc[1][1] += s.y * w.y; acc[1][2] += s.y * w.z; acc[1][3] += s.y * w.w;
            acc[2][0] += s.z * w.x; acc[2][1] += s.z * w.y; acc[2][2] += s.z * w.z; acc[2][3] += s.z * w.w;
            acc[3][0] += s.w * w.x; acc[3][1] += s.w * w.y; acc[3][2] += s.w * w.z; acc[3][3] += s.w * w.w;
        }
        #pragma unroll
        for (int r = 0; r < 4; r++) {
            const int row = rbase + rl0 + r;
            if (row < NNODES) {
                float4 xv = *(const float4*)(x + (size_t)row * NF + j0);
                float4 o;
                o.x = theta * acc[r][0] + omt * sT[(j0 + 0) * 32 + rl0 + r] + xv.x;
                o.y = theta * acc[r][1] + omt * sT[(j0 + 1) * 32 + rl0 + r] + xv.y;
                o.z = theta * acc[r][2] + omt * sT[(j0 + 2) * 32 + rl0 + r] + xv.z;
                o.w = theta * acc[r][3] + omt * sT[(j0 + 3) * 32 + rl0 + r] + xv.w;
                *(float4*)(S + (size_t)row * NF + j0) = o;
            }
        }
        __syncthreads();
    }
}

// ===========================================================================
extern "C" void kernel_launch(void* const* d_in, const int* in_sizes, int n_in,
                              void* d_out, int out_size, void* d_ws, size_t ws_size,
                              hipStream_t stream) {
    const float* x       = (const float*)d_in[0];
    const float* h0      = (const float*)d_in[1];
    const float* edge_w  = (const float*)d_in[2];
    const float* weight  = (const float*)d_in[3];
    const float* lamda   = (const float*)d_in[4];
    const float* alpha   = (const float*)d_in[5];
    const int*   srcp    = (const int*)d_in[6];
    const int*   dstp    = (const int*)d_in[7];
    const int*   l       = (const int*)d_in[8];
    float* out = (float*)d_out;

    // xcd path: cnt8 1.6 | ovf_cnt 0.2 | rec 12.8 | ovf_rec 3.2 | xh 12.8 = 30.6MB
    const size_t need_xcd = (size_t)NNODES * 8 * 4 + (size_t)NNODES * 4
                          + (size_t)NNODES * NODE_CAP * 4
                          + (size_t)NNODES * OVF_CAP * 4
                          + (size_t)NNODES * NF * 2;
    // r4 padded path: cnt 6.4 | rec 12.8 | xh 12.8 = 32MB
    const size_t need_pad = (size_t)NNODES * CPAD * 4 + (size_t)NNODES * NODE_CAP * 4
                          + (size_t)NNODES * NF * 2;
    // r2 path: cnt 0.2 | rec 12.8 | xh 12.8 = 25.8MB
    const size_t need_hx  = (size_t)NNODES * 4 + (size_t)NNODES * NODE_CAP * 4
                          + (size_t)NNODES * NF * 2;

    if (ws_size >= need_xcd) {
        int*      cnt8    = (int*)d_ws;
        int*      ovf_cnt = cnt8 + (size_t)NNODES * 8;
        unsigned* rec     = (unsigned*)(ovf_cnt + NNODES);
        unsigned* ovf_rec = rec + (size_t)NNODES * NODE_CAP;
        __half*   xh      = (__half*)(ovf_rec + (size_t)NNODES * OVF_CAP);

        hipMemsetAsync(cnt8, 0, (size_t)NNODES * 9 * sizeof(int), stream); // cnt8+ovf_cnt
        bin_fill_xcd<<<(NEDGES + 255) / 256, 256, 0, stream>>>(srcp, dstp, edge_w, alpha,
                                                               x, cnt8, ovf_cnt,
                                                               rec, ovf_rec, xh);
        fused_bin8<<<NTILES, 256, 0, stream>>>(x, xh, h0, alpha, lamda, l,
                                               cnt8, ovf_cnt, rec, ovf_rec,
                                               weight, out);
    } else if (ws_size >= need_pad) {
        int*      cnt = (int*)d_ws;
        unsigned* rec = (unsigned*)(cnt + (size_t)NNODES * CPAD);
        __half*   xh  = (__half*)(rec + (size_t)NNODES * NODE_CAP);

        hipMemsetAsync(cnt, 0, (size_t)NNODES * CPAD * sizeof(int), stream);
        bin_fill_conv_pad<<<(NEDGES + 255) / 256, 256, 0, stream>>>(srcp, dstp, edge_w,
                                                                    alpha, x, cnt, rec, xh);
        fused_bin7<<<NTILES, 256, 0, stream>>>(x, xh, h0, alpha, lamda, l,
                                               cnt, rec, weight, out);
    } else if (ws_size >= need_hx) {
        int*      cnt = (int*)d_ws;
        unsigned* rec = (unsigned*)(cnt + NNODES);
        __half*   xh  = (__half*)(rec + (size_t)NNODES * NODE_CAP);

        hipMemsetAsync(cnt, 0, NNODES * sizeof(int), stream);
        bin_fill_conv<<<(NEDGES + 255) / 256, 256, 0, stream>>>(srcp, dstp, edge_w, alpha,
                                                                x, cnt, rec, xh);
        fused_bin6<<<NTILES, 256, 0, stream>>>(x, xh, h0, alpha, lamda, l,
                                               cnt, rec, weight, out);
    } else {
        init_support<<<(NNODES * NF / 4 + 255) / 256, 256, 0, stream>>>(h0, alpha, out);
        scatter_edges<<<(NEDGES * 32 + 255) / 256, 256, 0, stream>>>(x, edge_w, srcp, dstp,
                                                                     alpha, out);
        gemm_out<<<GEMM_BLOCKS, 256, 0, stream>>>(out, weight, x, lamda, l);
    }
}

// Round 6
// 202.819 us; speedup vs baseline: 1.1373x; 1.1373x over previous
//
#include <hip/hip_runtime.h>
#include <hip/hip_fp16.h>
#include <math.h>

#define NNODES 50000
#define NF     128
#define NEDGES 800000

#define NTILES ((NNODES + 31) / 32)          // 1563
#define NODE_CAP 64                          // deg ~ Poisson(16); P(>=64) ~ 0
#define CPAD 32                              // counter stride (ints) = 128B/line
#define GEMM_BLOCKS 512

__device__ __forceinline__ unsigned bf16_rne(float f) {
    unsigned u = __float_as_uint(f);
    return (u + 0x7FFFu + ((u >> 16) & 1u)) >> 16;
}

struct alignas(8) half4v { __half2 lo, hi; };

// 8-feature fp16 gather: one 16B load -> 8 fma into f32 acc
__device__ __forceinline__ void gath8(float acc[8], const uint4 g, const float w) {
    const __half2* hp = (const __half2*)&g;
    #pragma unroll
    for (int k = 0; k < 4; k++) {
        const float2 f = __half22float2(hp[k]);
        acc[2 * k]     += w * f.x;
        acc[2 * k + 1] += w * f.y;
    }
}

// ============ bin fill + x->fp16 convert — r4 proven version ================
__global__ __launch_bounds__(256) void bin_fill_conv_pad(const int* __restrict__ src,
                                                         const int* __restrict__ dst,
                                                         const float* __restrict__ ew,
                                                         const float* __restrict__ alpha_p,
                                                         const float* __restrict__ x,
                                                         int* __restrict__ cnt,
                                                         unsigned* __restrict__ rec,
                                                         __half* __restrict__ xh) {
    int e = blockIdx.x * 256 + threadIdx.x;
    if (e >= NEDGES) return;

    // ---- convert 8 x elements -> fp16 (streamed, coalesced) ----
    {
        const float4 a = *(const float4*)(x + (size_t)e * 8);
        const float4 b = *(const float4*)(x + (size_t)e * 8 + 4);
        __half2 p0 = __floats2half2_rn(a.x, a.y);
        __half2 p1 = __floats2half2_rn(a.z, a.w);
        __half2 p2 = __floats2half2_rn(b.x, b.y);
        __half2 p3 = __floats2half2_rn(b.z, b.w);
        uint4 o;
        o.x = *(const unsigned*)&p0;
        o.y = *(const unsigned*)&p1;
        o.z = *(const unsigned*)&p2;
        o.w = *(const unsigned*)&p3;
        *(uint4*)(xh + (size_t)e * 8) = o;
    }

    // ---- bin the edge (padded counter: one per 128B line) ----
    const int d = dst[e];
    const int pos = atomicAdd(&cnt[(size_t)d * CPAD], 1);
    if (pos < NODE_CAP) {
        const unsigned wb = bf16_rne((1.0f - alpha_p[0]) * ew[e]);
        rec[(size_t)d * NODE_CAP + pos] = (wb << 16) | (unsigned)src[e];
    }
}

// ==== fused: quarter-wave gather (16B/lane, 16 loads in flight/wave) ========
// r4 counters: 71.5us, FETCH 106MB @1.48TB/s (below the 2.16 TB/s fabric
// ceiling seen at f32), VALUBusy 37% -> latency-bound, not BW-bound.
// Phase 1 rework: each QUARTER-wave (16 lanes) owns a node; lane covers 8
// features (16B = dwordx4 loads, coalescing sweet spot). 4 nodes/wave in
// flight x 4-deep record unroll = 16 independent gathers/wave (2x r4).
// Per-feature edge-order unchanged -> bit-identical output vs r4.
__global__ __launch_bounds__(256)
void fused_bin9(const float* __restrict__ x,
                const __half* __restrict__ xh,
                const float* __restrict__ h0,
                const float* __restrict__ alpha_p,
                const float* __restrict__ lamda_p,
                const int* __restrict__ l_p,
                const int* __restrict__ cnt,
                const unsigned* __restrict__ rec,
                const float* __restrict__ W,
                float* __restrict__ out) {
    __shared__ float sT[32 * NF];   // 16 KB, row-major [row][feat]

    const int tid   = threadIdx.x;
    const int wave  = tid >> 6;
    const int lane  = tid & 63;
    const int nq    = lane >> 4;          // quarter-wave id 0..3 -> node
    const int j0    = (lane & 15) * 8;    // 8-feature chunk
    const int rbase = blockIdx.x * 32;
    const float alpha = alpha_p[0];

    int cnts[2];
    #pragma unroll
    for (int p = 0; p < 2; p++) {
        const int node = rbase + wave * 8 + p * 4 + nq;
        cnts[p] = (node < NNODES) ? cnt[(size_t)node * CPAD] : 0;
    }

    #pragma unroll
    for (int p = 0; p < 2; p++) {
        const int rl   = wave * 8 + p * 4 + nq;
        const int node = rbase + rl;

        float acc[8];
        #pragma unroll
        for (int k = 0; k < 8; k++) acc[k] = 0.f;

        if (node < NNODES) {
            const float4 ha = *(const float4*)(h0 + (size_t)node * NF + j0);
            const float4 hb = *(const float4*)(h0 + (size_t)node * NF + j0 + 4);
            acc[0] = alpha * ha.x; acc[1] = alpha * ha.y;
            acc[2] = alpha * ha.z; acc[3] = alpha * ha.w;
            acc[4] = alpha * hb.x; acc[5] = alpha * hb.y;
            acc[6] = alpha * hb.z; acc[7] = alpha * hb.w;

            const int count = min(cnts[p], NODE_CAP);
            const unsigned* brec = rec + (size_t)node * NODE_CAP;
            int i = 0;
            for (; i + 3 < count; i += 4) {
                const uint4 r = *(const uint4*)(brec + i);
                const uint4 g0 = *(const uint4*)(xh + (size_t)(r.x & 0xFFFFu) * NF + j0);
                const uint4 g1 = *(const uint4*)(xh + (size_t)(r.y & 0xFFFFu) * NF + j0);
                const uint4 g2 = *(const uint4*)(xh + (size_t)(r.z & 0xFFFFu) * NF + j0);
                const uint4 g3 = *(const uint4*)(xh + (size_t)(r.w & 0xFFFFu) * NF + j0);
                gath8(acc, g0, __uint_as_float(r.x & 0xFFFF0000u));
                gath8(acc, g1, __uint_as_float(r.y & 0xFFFF0000u));
                gath8(acc, g2, __uint_as_float(r.z & 0xFFFF0000u));
                gath8(acc, g3, __uint_as_float(r.w & 0xFFFF0000u));
            }
            for (; i < count; i++) {
                const unsigned rv = brec[i];
                const uint4 g = *(const uint4*)(xh + (size_t)(rv & 0xFFFFu) * NF + j0);
                gath8(acc, g, __uint_as_float(rv & 0xFFFF0000u));
            }
        }
        *(float4*)&sT[rl * NF + j0]     = make_float4(acc[0], acc[1], acc[2], acc[3]);
        *(float4*)&sT[rl * NF + j0 + 4] = make_float4(acc[4], acc[5], acc[6], acc[7]);
    }
    __syncthreads();

    // ---- phase 2: 32x128 tile GEMM (unchanged, proven) ----
    const int cg_  = tid & 31;
    const int slot = tid >> 5;
    const int jj   = cg_ * 4;
    const int r0_  = slot * 4;

    float acc[4][4];
    #pragma unroll
    for (int r = 0; r < 4; r++)
        #pragma unroll
        for (int c = 0; c < 4; c++) acc[r][c] = 0.f;

    #pragma unroll 4
    for (int k = 0; k < NF; k++) {
        const float4 w = *(const float4*)(W + k * NF + jj);   // L1/L2 hit
        const float s0 = sT[(r0_ + 0) * NF + k];              // broadcast reads
        const float s1 = sT[(r0_ + 1) * NF + k];
        const float s2 = sT[(r0_ + 2) * NF + k];
        const float s3 = sT[(r0_ + 3) * NF + k];
        acc[0][0] += s0 * w.x; acc[0][1] += s0 * w.y; acc[0][2] += s0 * w.z; acc[0][3] += s0 * w.w;
        acc[1][0] += s1 * w.x; acc[1][1] += s1 * w.y; acc[1][2] += s1 * w.z; acc[1][3] += s1 * w.w;
        acc[2][0] += s2 * w.x; acc[2][1] += s2 * w.y; acc[2][2] += s2 * w.z; acc[2][3] += s2 * w.w;
        acc[3][0] += s3 * w.x; acc[3][1] += s3 * w.y; acc[3][2] += s3 * w.z; acc[3][3] += s3 * w.w;
    }

    const float theta = logf(lamda_p[0] / (float)l_p[0] + 1.0f);
    const float omt   = 1.0f - theta;

    #pragma unroll
    for (int r = 0; r < 4; r++) {
        const int row = rbase + r0_ + r;
        if (row < NNODES) {
            const float4 xv = *(const float4*)(x + (size_t)row * NF + jj);
            const float4 s  = *(const float4*)&sT[(r0_ + r) * NF + jj];
            float4 o;
            o.x = theta * acc[r][0] + omt * s.x + xv.x;
            o.y = theta * acc[r][1] + omt * s.y + xv.y;
            o.z = theta * acc[r][2] + omt * s.z + xv.z;
            o.w = theta * acc[r][3] + omt * s.w + xv.w;
            *(float4*)(out + (size_t)row * NF + jj) = o;
        }
    }
}

// ============ r2 fallback: unpadded counters ================================

__global__ __launch_bounds__(256) void bin_fill_conv(const int* __restrict__ src,
                                                     const int* __restrict__ dst,
                                                     const float* __restrict__ ew,
                                                     const float* __restrict__ alpha_p,
                                                     const float* __restrict__ x,
                                                     int* __restrict__ cnt,
                                                     unsigned* __restrict__ rec,
                                                     __half* __restrict__ xh) {
    int e = blockIdx.x * 256 + threadIdx.x;
    if (e >= NEDGES) return;
    {
        const float4 a = *(const float4*)(x + (size_t)e * 8);
        const float4 b = *(const float4*)(x + (size_t)e * 8 + 4);
        __half2 p0 = __floats2half2_rn(a.x, a.y);
        __half2 p1 = __floats2half2_rn(a.z, a.w);
        __half2 p2 = __floats2half2_rn(b.x, b.y);
        __half2 p3 = __floats2half2_rn(b.z, b.w);
        uint4 o;
        o.x = *(const unsigned*)&p0;
        o.y = *(const unsigned*)&p1;
        o.z = *(const unsigned*)&p2;
        o.w = *(const unsigned*)&p3;
        *(uint4*)(xh + (size_t)e * 8) = o;
    }
    const int d = dst[e];
    const int pos = atomicAdd(&cnt[d], 1);
    if (pos < NODE_CAP) {
        const unsigned wb = bf16_rne((1.0f - alpha_p[0]) * ew[e]);
        rec[(size_t)d * NODE_CAP + pos] = (wb << 16) | (unsigned)src[e];
    }
}

__global__ __launch_bounds__(256)
void fused_bin6(const float* __restrict__ x,
                const __half* __restrict__ xh,
                const float* __restrict__ h0,
                const float* __restrict__ alpha_p,
                const float* __restrict__ lamda_p,
                const int* __restrict__ l_p,
                const int* __restrict__ cnt,
                const unsigned* __restrict__ rec,
                const float* __restrict__ W,
                float* __restrict__ out) {
    __shared__ float sT[32 * NF];

    const int tid   = threadIdx.x;
    const int wave  = tid >> 6;
    const int lane  = tid & 63;
    const int eh    = lane >> 5;
    const int j0    = (lane & 31) * 4;
    const int rbase = blockIdx.x * 32;
    const float alpha = alpha_p[0];

    const int nbase = rbase + wave * 8 + eh;

    int cnts[4];
    #pragma unroll
    for (int q = 0; q < 4; q++) {
        const int node = nbase + 2 * q;
        cnts[q] = (node < NNODES) ? cnt[node] : 0;
    }

    #pragma unroll
    for (int q = 0; q < 4; q++) {
        const int node = nbase + 2 * q;
        const int rl   = wave * 8 + 2 * q + eh;

        float4 acc = make_float4(0.f, 0.f, 0.f, 0.f);
        if (node < NNODES) {
            const float4 h = *(const float4*)(h0 + (size_t)node * NF + j0);
            acc.x = alpha * h.x;
            acc.y = alpha * h.y;
            acc.z = alpha * h.z;
            acc.w = alpha * h.w;

            const int count = min(cnts[q], NODE_CAP);
            const unsigned* brec = rec + (size_t)node * NODE_CAP;
            int i = 0;
            for (; i + 3 < count; i += 4) {
                const uint4 r = *(const uint4*)(brec + i);
                #pragma unroll
                for (int t = 0; t < 4; t++) {
                    const unsigned rv = (&r.x)[t];
                    const half4v v = *(const half4v*)(xh + (size_t)(rv & 0xFFFFu) * NF + j0);
                    const float w = __uint_as_float(rv & 0xFFFF0000u);
                    const float2 f0 = __half22float2(v.lo), f1 = __half22float2(v.hi);
                    acc.x += w * f0.x; acc.y += w * f0.y; acc.z += w * f1.x; acc.w += w * f1.y;
                }
            }
            for (; i < count; i++) {
                const unsigned rv = brec[i];
                const half4v v = *(const half4v*)(xh + (size_t)(rv & 0xFFFFu) * NF + j0);
                const float w = __uint_as_float(rv & 0xFFFF0000u);
                const float2 f0 = __half22float2(v.lo), f1 = __half22float2(v.hi);
                acc.x += w * f0.x; acc.y += w * f0.y; acc.z += w * f1.x; acc.w += w * f1.y;
            }
        }
        *(float4*)&sT[rl * NF + j0] = acc;
    }
    __syncthreads();

    const int cg_  = tid & 31;
    const int slot = tid >> 5;
    const int jj   = cg_ * 4;
    const int r0_  = slot * 4;

    float acc[4][4];
    #pragma unroll
    for (int r = 0; r < 4; r++)
        #pragma unroll
        for (int c = 0; c < 4; c++) acc[r][c] = 0.f;

    #pragma unroll 4
    for (int k = 0; k < NF; k++) {
        const float4 w = *(const float4*)(W + k * NF + jj);
        const float s0 = sT[(r0_ + 0) * NF + k];
        const float s1 = sT[(r0_ + 1) * NF + k];
        const float s2 = sT[(r0_ + 2) * NF + k];
        const float s3 = sT[(r0_ + 3) * NF + k];
        acc[0][0] += s0 * w.x; acc[0][1] += s0 * w.y; acc[0][2] += s0 * w.z; acc[0][3] += s0 * w.w;
        acc[1][0] += s1 * w.x; acc[1][1] += s1 * w.y; acc[1][2] += s1 * w.z; acc[1][3] += s1 * w.w;
        acc[2][0] += s2 * w.x; acc[2][1] += s2 * w.y; acc[2][2] += s2 * w.z; acc[2][3] += s2 * w.w;
        acc[3][0] += s3 * w.x; acc[3][1] += s3 * w.y; acc[3][2] += s3 * w.z; acc[3][3] += s3 * w.w;
    }

    const float theta = logf(lamda_p[0] / (float)l_p[0] + 1.0f);
    const float omt   = 1.0f - theta;

    #pragma unroll
    for (int r = 0; r < 4; r++) {
        const int row = rbase + r0_ + r;
        if (row < NNODES) {
            const float4 xv = *(const float4*)(x + (size_t)row * NF + jj);
            const float4 s  = *(const float4*)&sT[(r0_ + r) * NF + jj];
            float4 o;
            o.x = theta * acc[r][0] + omt * s.x + xv.x;
            o.y = theta * acc[r][1] + omt * s.y + xv.y;
            o.z = theta * acc[r][2] + omt * s.z + xv.z;
            o.w = theta * acc[r][3] + omt * s.w + xv.w;
            *(float4*)(out + (size_t)row * NF + jj) = o;
        }
    }
}

// ===================== round-1 ultimate fallback =============================

__global__ __launch_bounds__(256) void init_support(const float* __restrict__ h0,
                                                    const float* __restrict__ alpha_p,
                                                    float* __restrict__ S) {
    const float alpha = alpha_p[0];
    int i = (blockIdx.x * 256 + threadIdx.x) * 4;
    if (i < NNODES * NF) {
        float4 h = *(const float4*)(h0 + i);
        float4 v;
        v.x = alpha * h.x; v.y = alpha * h.y; v.z = alpha * h.z; v.w = alpha * h.w;
        *(float4*)(S + i) = v;
    }
}

__global__ __launch_bounds__(256) void scatter_edges(const float* __restrict__ x,
                                                     const float* __restrict__ ew,
                                                     const int* __restrict__ src,
                                                     const int* __restrict__ dst,
                                                     const float* __restrict__ alpha_p,
                                                     float* __restrict__ S) {
    int gid  = blockIdx.x * 256 + threadIdx.x;
    int e    = gid >> 5;
    int lane = gid & 31;
    if (e >= NEDGES) return;
    const float coef = (1.0f - alpha_p[0]) * ew[e];
    const int s = src[e];
    const int d = dst[e];
    const float4 xs = *(const float4*)(x + (long)s * NF + lane * 4);
    float* outp = S + (long)d * NF + lane * 4;
    unsafeAtomicAdd(outp + 0, coef * xs.x);
    unsafeAtomicAdd(outp + 1, coef * xs.y);
    unsafeAtomicAdd(outp + 2, coef * xs.z);
    unsafeAtomicAdd(outp + 3, coef * xs.w);
}

__global__ __launch_bounds__(256) void gemm_out(float* __restrict__ S,
                                                const float* __restrict__ W,
                                                const float* __restrict__ x,
                                                const float* __restrict__ lamda_p,
                                                const int* __restrict__ l_p) {
    __shared__ float Wl[NF * NF];
    __shared__ float sT[NF * 32];
    const int tid = threadIdx.x;
    {
        const float4* Wv = (const float4*)W;
        float4* Wlv = (float4*)Wl;
        #pragma unroll
        for (int i = 0; i < 16; i++) Wlv[tid + i * 256] = Wv[tid + i * 256];
    }
    const float theta = logf(lamda_p[0] / (float)l_p[0] + 1.0f);
    const float omt   = 1.0f - theta;
    const int cg_ = tid & 31, slot = tid >> 5;
    const int j0 = cg_ * 4, rl0 = slot * 4;
    const int rl = tid & 31, c0 = (tid >> 5) * 16;

    for (int t = blockIdx.x; t < NTILES; t += GEMM_BLOCKS) {
        const int rbase = t * 32;
        {
            const int row = rbase + rl;
            #pragma unroll
            for (int cc = 0; cc < 16; cc += 4) {
                const int c = c0 + cc;
                float4 v = (row < NNODES) ? *(const float4*)(S + (size_t)row * NF + c)
                                          : make_float4(0.f, 0.f, 0.f, 0.f);
                sT[(c + 0) * 32 + rl] = v.x;
                sT[(c + 1) * 32 + rl] = v.y;
                sT[(c + 2) * 32 + rl] = v.z;
                sT[(c + 3) * 32 + rl] = v.w;
            }
        }
        __syncthreads();
        float acc[4][4];
        #pragma unroll
        for (int r = 0; r < 4; r++)
            #pragma unroll
            for (int c = 0; c < 4; c++) acc[r][c] = 0.f;
        #pragma unroll 4
        for (int k = 0; k < NF; k++) {
            float4 w = *(const float4*)&Wl[k * NF + j0];
            float4 s = *(const float4*)&sT[k * 32 + rl0];
            acc[0][0] += s.x * w.x; acc[0][1] += s.x * w.y; acc[0][2] += s.x * w.z; acc[0][3] += s.x * w.w;
            acc[1][0] += s.y * w.x; acc[1][1] += s.y * w.y; acc[1][2] += s.y * w.z; acc[1][3] += s.y * w.w;
            acc[2][0] += s.z * w.x; acc[2][1] += s.z * w.y; acc[2][2] += s.z * w.z; acc[2][3] += s.z * w.w;
            acc[3][0] += s.w * w.x; acc[3][1] += s.w * w.y; acc[3][2] += s.w * w.z; acc[3][3] += s.w * w.w;
        }
        #pragma unroll
        for (int r = 0; r < 4; r++) {
            const int row = rbase + rl0 + r;
            if (row < NNODES) {
                float4 xv = *(const float4*)(x + (size_t)row * NF + j0);
                float4 o;
                o.x = theta * acc[r][0] + omt * sT[(j0 + 0) * 32 + rl0 + r] + xv.x;
                o.y = theta * acc[r][1] + omt * sT[(j0 + 1) * 32 + rl0 + r] + xv.y;
                o.z = theta * acc[r][2] + omt * sT[(j0 + 2) * 32 + rl0 + r] + xv.z;
                o.w = theta * acc[r][3] + omt * sT[(j0 + 3) * 32 + rl0 + r] + xv.w;
                *(float4*)(S + (size_t)row * NF + j0) = o;
            }
        }
        __syncthreads();
    }
}

// ===========================================================================
extern "C" void kernel_launch(void* const* d_in, const int* in_sizes, int n_in,
                              void* d_out, int out_size, void* d_ws, size_t ws_size,
                              hipStream_t stream) {
    const float* x       = (const float*)d_in[0];
    const float* h0      = (const float*)d_in[1];
    const float* edge_w  = (const float*)d_in[2];
    const float* weight  = (const float*)d_in[3];
    const float* lamda   = (const float*)d_in[4];
    const float* alpha   = (const float*)d_in[5];
    const int*   srcp    = (const int*)d_in[6];
    const int*   dstp    = (const int*)d_in[7];
    const int*   l       = (const int*)d_in[8];
    float* out = (float*)d_out;

    // padded path: cnt 6.4 | rec 12.8 | xh 12.8 = 32MB
    const size_t need_pad = (size_t)NNODES * CPAD * 4 + (size_t)NNODES * NODE_CAP * 4
                          + (size_t)NNODES * NF * 2;
    // r2 path: cnt 0.2 | rec 12.8 | xh 12.8 = 25.8MB
    const size_t need_hx  = (size_t)NNODES * 4 + (size_t)NNODES * NODE_CAP * 4
                          + (size_t)NNODES * NF * 2;

    if (ws_size >= need_pad) {
        int*      cnt = (int*)d_ws;
        unsigned* rec = (unsigned*)(cnt + (size_t)NNODES * CPAD);
        __half*   xh  = (__half*)(rec + (size_t)NNODES * NODE_CAP);

        hipMemsetAsync(cnt, 0, (size_t)NNODES * CPAD * sizeof(int), stream);
        bin_fill_conv_pad<<<(NEDGES + 255) / 256, 256, 0, stream>>>(srcp, dstp, edge_w,
                                                                    alpha, x, cnt, rec, xh);
        fused_bin9<<<NTILES, 256, 0, stream>>>(x, xh, h0, alpha, lamda, l,
                                               cnt, rec, weight, out);
    } else if (ws_size >= need_hx) {
        int*      cnt = (int*)d_ws;
        unsigned* rec = (unsigned*)(cnt + NNODES);
        __half*   xh  = (__half*)(rec + (size_t)NNODES * NODE_CAP);

        hipMemsetAsync(cnt, 0, NNODES * sizeof(int), stream);
        bin_fill_conv<<<(NEDGES + 255) / 256, 256, 0, stream>>>(srcp, dstp, edge_w, alpha,
                                                                x, cnt, rec, xh);
        fused_bin6<<<NTILES, 256, 0, stream>>>(x, xh, h0, alpha, lamda, l,
                                               cnt, rec, weight, out);
    } else {
        init_support<<<(NNODES * NF / 4 + 255) / 256, 256, 0, stream>>>(h0, alpha, out);
        scatter_edges<<<(NEDGES * 32 + 255) / 256, 256, 0, stream>>>(x, edge_w, srcp, dstp,
                                                                     alpha, out);
        gemm_out<<<GEMM_BLOCKS, 256, 0, stream>>>(out, weight, x, lamda, l);
    }
}